// Round 1
// baseline (175.110 us; speedup 1.0000x reference)
//
#include <hip/hip_runtime.h>
#include <hip/hip_bf16.h>

#define H 1024
#define B 64

// Kernel A: u[b,h] = sum_k hidden[b,k] * W[k,h];  c[b] = sum_k hidden[b,k]*bias[k]
__global__ __launch_bounds__(256) void proj_hidden_kernel(
    const float* __restrict__ hidden,   // [B, H] (hidden[0])
    const float* __restrict__ W,        // [H, H] row-major (W[k*H + h])
    const float* __restrict__ bias,     // [H]
    float* __restrict__ u,              // [B, H] out
    float* __restrict__ c)              // [B] out
{
    const int b = blockIdx.y;
    const int h = blockIdx.x * 256 + threadIdx.x;
    const float* hb = hidden + b * H;

    float acc = 0.f;
    #pragma unroll 8
    for (int k = 0; k < H; ++k) {
        acc += hb[k] * W[(size_t)k * H + h];   // coalesced across threads (h contiguous)
    }
    u[(size_t)b * H + h] = acc;

    if (blockIdx.x == 0) {
        float s = 0.f;
        for (int k = threadIdx.x; k < H; k += 256) s += hb[k] * bias[k];
        __shared__ float red[256];
        red[threadIdx.x] = s;
        __syncthreads();
        for (int st = 128; st > 0; st >>= 1) {
            if (threadIdx.x < st) red[threadIdx.x] += red[threadIdx.x + st];
            __syncthreads();
        }
        if (threadIdx.x == 0) c[b] = red[0];
    }
}

// Kernel B: one block per l. energy[b] = dot(u[b], enc[l,b]) + c[b]; softmax over b;
// out[b*L + l] = softmax result.
__global__ __launch_bounds__(1024) void energy_softmax_kernel(
    const float* __restrict__ enc,   // [L, B, H]
    const float* __restrict__ u,     // [B, H]
    const float* __restrict__ c,     // [B]
    float* __restrict__ out,         // [B, L] flat (B,1,L)
    int L)
{
    const int l    = blockIdx.x;
    const int tid  = threadIdx.x;
    const int wave = tid >> 6;    // 0..15
    const int lane = tid & 63;

    __shared__ float e_s[B];

    const float* encl = enc + (size_t)l * B * H;

    // 16 waves, each handles 4 consecutive b rows
    #pragma unroll
    for (int i = 0; i < 4; ++i) {
        const int b = wave * 4 + i;
        const float4* ep = (const float4*)(encl + (size_t)b * H);
        const float4* up = (const float4*)(u + (size_t)b * H);
        float acc = 0.f;
        #pragma unroll
        for (int j = 0; j < 4; ++j) {
            float4 ev = ep[lane + j * 64];   // coalesced: 64 lanes x 16B
            float4 uv = up[lane + j * 64];
            acc += ev.x * uv.x + ev.y * uv.y + ev.z * uv.z + ev.w * uv.w;
        }
        // wave-wide sum (64 lanes)
        for (int off = 32; off > 0; off >>= 1)
            acc += __shfl_down(acc, off, 64);
        if (lane == 0) e_s[b] = acc + c[b];
    }
    __syncthreads();

    // wave 0 (threads 0..63) does the 64-wide softmax over b
    if (tid < B) {
        float e = e_s[tid];
        float m = e;
        for (int off = 32; off > 0; off >>= 1)
            m = fmaxf(m, __shfl_xor(m, off, 64));
        float ex = expf(e - m);
        float s = ex;
        for (int off = 32; off > 0; off >>= 1)
            s += __shfl_xor(s, off, 64);
        out[(size_t)tid * L + l] = ex / s;
    }
}

extern "C" void kernel_launch(void* const* d_in, const int* in_sizes, int n_in,
                              void* d_out, int out_size, void* d_ws, size_t ws_size,
                              hipStream_t stream) {
    const float* hidden = (const float*)d_in[0];  // [1, 64, 1024]
    const float* enc    = (const float*)d_in[1];  // [L, 64, 1024]
    const float* W      = (const float*)d_in[2];  // [1024, 1024]
    const float* bias   = (const float*)d_in[3];  // [1024]
    float* out = (float*)d_out;                   // [64, 1, L]

    const int L = in_sizes[1] / (B * H);          // 2048

    float* u = (float*)d_ws;                      // B*H floats = 256 KiB
    float* c = u + (size_t)B * H;                 // B floats

    dim3 gridA(H / 256, B);
    proj_hidden_kernel<<<gridA, 256, 0, stream>>>(hidden, W, bias, u, c);

    energy_softmax_kernel<<<L, 1024, 0, stream>>>(enc, u, c, out, L);
}